// Round 10
// baseline (251.416 us; speedup 1.0000x reference)
//
#include <hip/hip_runtime.h>

// P2B_XCorr: B=8, F=128, M=256, N=1024, H=64, O=128. fp32 I/O.
// R10: revert R9's fusion (FETCH 120 MB — L2 thrash), keep its wins on the proven
//   R8 split structure:
//   - k_main grid (64,8,2)=1024 blocks (4/CU): 16 n per block, 4 waves split m 4-way
//     over the SAME n-columns -> one 16x16 B-frag/step, 4-way LDS max combine (no
//     write race). Double-buffered h2, one lgkmcnt(0) per 2 m-steps, prefetch before
//     the barrier. bias c3 + relu folded into the partial store (monotone-commute).
//   - k_prep norm threads also emit f16-packed tH/sH; k_cos stages from them
//     (half the staging bytes, no pack VALU).
//   - P partials overlay tH/sH (dead after k_cos); ws stays in proven 8.59 MiB.
// Frag layouts (HW-verified): A[m=lane&15][k=quad*8+j], B[k=quad*8+j][n=lane&15],
// D[row=quad*4+reg][col=lane&15].

#define BB 8
#define FF 128
#define MM 256
#define NN 1024
#define HH 64
#define OO 128
#define BN_EPS 1e-5f
#define COS_EPS 1e-8f

// ws layout (float offsets); max used 2,175,232 < proven 2,251,008 envelope
#define WS_U     0
#define WS_C2    64
#define WS_C3    128
#define WS_CC1   192
#define WS_W2F   256
#define WS_W3F   4352
#define WS_WC1F  8448
#define WS_A1    12544        // f16 A1H[b][m][64] -> ends 78080
#define WS_COSH  78080        // f16 cos[b][m][n] -> ends 1,126,656
#define WS_TH    1126656      // u32 tH[b][64 fpair][256 m] -> ends 1,257,728 (k_cos only)
#define WS_SH    1257728      // u32 sH[b][64 fpair][1024 n] -> ends 1,782,016 (k_cos only)
#define WS_NT    1782016      // fp32 [b][m] (k_cos only)
#define WS_NS    1784064      // fp32 [b][n] -> ends 1,792,256 (k_cos only)
#define WS_P     1126656      // OVERLAY on TH.. : fp32 partials [2][b][n][64] -> ends 2,175,232
#define PS       524288

typedef _Float16 half2v __attribute__((ext_vector_type(2)));
typedef _Float16 half8  __attribute__((ext_vector_type(8)));
typedef __attribute__((ext_vector_type(4))) float f32x4;

__device__ __forceinline__ unsigned int pkh2(float a, float b){
  auto h = __builtin_amdgcn_cvt_pkrtz(a, b);
  return __builtin_bit_cast(unsigned int, h);
}
__device__ __forceinline__ half2v u2h(unsigned int u){
  return __builtin_bit_cast(half2v, u);
}
__device__ __forceinline__ unsigned int h2u(half2v v){
  return __builtin_bit_cast(unsigned int, v);
}
__device__ __forceinline__ unsigned int relu2(unsigned int d){
  half2v v = __builtin_elementwise_max(u2h(d), (half2v){(_Float16)0, (_Float16)0});
  return h2u(v);
}
__device__ __forceinline__ unsigned int bh1(unsigned int up, half2v c, unsigned int ap){
  half2v v = __builtin_elementwise_fma(u2h(up), c, u2h(ap));
  v = __builtin_elementwise_max(v, (half2v){(_Float16)0, (_Float16)0});
  return h2u(v);
}
__device__ __forceinline__ float dot4(float4 a, float4 b, float acc){
  acc = fmaf(a.x, b.x, acc); acc = fmaf(a.y, b.y, acc);
  acc = fmaf(a.z, b.z, acc); acc = fmaf(a.w, b.w, acc);
  return acc;
}

// ---------------- K1: prep (role-split: a1 | norms+f16 pack | fold) ----------------
__global__ __launch_bounds__(256) void k_prep(const float* t_, const float* s_,
    const float* W1, const float* W2, const float* W3, const float* Wc1,
    const float* g1, const float* b1, const float* m1, const float* v1,
    const float* g2, const float* b2, const float* m2, const float* v2,
    const float* g3, const float* b3, const float* m3, const float* v3,
    const float* gc1,const float* bc1,const float* mc1,const float* vc1,
    float* ws){
  __shared__ float W1s[64][133];
  int t = threadIdx.x;
  int bx = blockIdx.x;
  if (bx < 256){
    // ---- A1H[b][m][h] (f16) ----
    int b = bx >> 5, m0 = (bx & 31)*8;
    for (int idx = t; idx < 8192; idx += 256){
      int h = idx >> 7, f = idx & 127;
      W1s[h][f] = W1[h*129 + 1 + f];
    }
    __syncthreads();
    int h = t & 63, mg = t >> 6;
    const float* tp = t_ + (size_t)b*FF*MM + m0 + mg*2;
    float acc0 = 0.f, acc1 = 0.f;
    for (int f = 0; f < FF; f++){
      float wv = W1s[h][f];
      float2 tv = *(const float2*)&tp[(size_t)f*MM];
      acc0 = fmaf(wv, tv.x, acc0); acc1 = fmaf(wv, tv.y, acc1);
    }
    float a1 = g1[h] / sqrtf(v1[h] + BN_EPS);
    float c1 = b1[h] - a1*m1[h];
    unsigned short* dst = (unsigned short*)(ws + WS_A1) + ((size_t)(b*MM + m0 + mg*2))*64 + h;
    dst[0]  = (unsigned short)(pkh2(fmaf(a1, acc0, c1), 0.f) & 0xFFFFu);
    dst[64] = (unsigned short)(pkh2(fmaf(a1, acc1, c1), 0.f) & 0xFFFFu);
  } else if (bx < 416){
    // ---- norms + f16 pack of t/s ----
    __shared__ float red[4][64];
    unsigned int* thp = (unsigned int*)(ws + WS_TH);
    unsigned int* shp = (unsigned int*)(ws + WS_SH);
    int x = t & 63, fq = t >> 6;
    int idx = (bx - 256)*64 + x;
    float acc = 0.f;
    if (idx < BB*MM){
      int b = idx >> 8, m = idx & 255;
      const float* ptr = t_ + (size_t)b*FF*MM + m;
      #pragma unroll
      for (int k = 0; k < 16; k++){
        int f = fq*32 + 2*k;
        float va = ptr[(size_t)f*MM], vb = ptr[(size_t)(f+1)*MM];
        acc = fmaf(va, va, acc); acc = fmaf(vb, vb, acc);
        thp[(size_t)(b*64 + fq*16 + k)*MM + m] = pkh2(va, vb);
      }
    } else {
      int j = idx - BB*MM;
      int b = j >> 10, n = j & 1023;
      const float* ptr = s_ + (size_t)b*FF*NN + n;
      #pragma unroll
      for (int k = 0; k < 16; k++){
        int f = fq*32 + 2*k;
        float va = ptr[(size_t)f*NN], vb = ptr[(size_t)(f+1)*NN];
        acc = fmaf(va, va, acc); acc = fmaf(vb, vb, acc);
        shp[(size_t)(b*64 + fq*16 + k)*NN + n] = pkh2(va, vb);
      }
    }
    red[fq][x] = acc;
    __syncthreads();
    if (fq == 0)
      ws[WS_NT + idx] = sqrtf(red[0][x] + red[1][x] + red[2][x] + red[3][x]);
  } else {
    // ---- fold ----
    if (t < 64){
      float a1 = g1[t] / sqrtf(v1[t] + BN_EPS);
      ws[WS_U + t]   = a1 * W1[t*129];
      float a2 = g2[t] / sqrtf(v2[t] + BN_EPS);
      ws[WS_C2 + t]  = b2[t] - a2*m2[t];
      float a3 = g3[t] / sqrtf(v3[t] + BN_EPS);
      ws[WS_C3 + t]  = b3[t] - a3*m3[t];
      float ac = gc1[t] / sqrtf(vc1[t] + BN_EPS);
      ws[WS_CC1 + t] = bc1[t] - ac*mc1[t];
    }
    for (int i = t; i < 4096; i += 256){
      int g = i >> 6;
      float a2 = g2[g] / sqrtf(v2[g] + BN_EPS);
      ws[WS_W2F + i]  = a2 * W2[i];
      float a3 = g3[g] / sqrtf(v3[g] + BN_EPS);
      ws[WS_W3F + i]  = a3 * W3[i];
      float ac = gc1[g] / sqrtf(vc1[g] + BN_EPS);
      ws[WS_WC1F + i] = ac * Wc1[i];
    }
  }
}

// ---------------- K2: cos via f16 MFMA, staged from packed tH/sH ----------------
__global__ __launch_bounds__(256) void k_cos(float* ws){
  __shared__ __align__(16) unsigned short tS[64][136];
  __shared__ __align__(16) unsigned short sS[64][136];
  __shared__ float ntS[64], nsS[64];
  int t = threadIdx.x;
  int lane = t & 63, w = t >> 6;
  int ln15 = lane & 15, quad = lane >> 4;
  int m0 = blockIdx.x*64, n0 = blockIdx.y*64, b = blockIdx.z;
  {
    const unsigned int* thp = (const unsigned int*)(ws + WS_TH);
    const unsigned int* shp = (const unsigned int*)(ws + WS_SH);
    for (int i = t; i < 4096; i += 256){
      int x = i & 63, fp = i >> 6;
      *(unsigned int*)&tS[x][2*fp] = thp[(size_t)(b*64 + fp)*MM + m0 + x];
      *(unsigned int*)&sS[x][2*fp] = shp[(size_t)(b*64 + fp)*NN + n0 + x];
    }
    if (t < 64) ntS[t] = ws[WS_NT + b*MM + m0 + t];
    else if (t < 128) nsS[t-64] = ws[WS_NS + b*NN + n0 + (t-64)];
  }
  __syncthreads();
  half8 A4[4];
  #pragma unroll
  for (int kc = 0; kc < 4; kc++)
    A4[kc] = *(const half8*)&tS[w*16 + ln15][kc*32 + quad*8];
  float4 nt4 = *(const float4*)&ntS[w*16 + quad*4];
  unsigned short* cosw = (unsigned short*)(ws + WS_COSH);
  #pragma unroll
  for (int ns = 0; ns < 4; ns++){
    f32x4 acc = (f32x4){0.f,0.f,0.f,0.f};
    #pragma unroll
    for (int kc = 0; kc < 4; kc++){
      half8 B4 = *(const half8*)&sS[ns*16 + ln15][kc*32 + quad*8];
      acc = __builtin_amdgcn_mfma_f32_16x16x32_f16(A4[kc], B4, acc, 0, 0, 0);
    }
    float nsv = nsS[ns*16 + ln15];
    int n = n0 + ns*16 + ln15;
    #pragma unroll
    for (int r = 0; r < 4; r++){
      int m = m0 + w*16 + quad*4 + r;
      float denom = fmaxf(nt4[r]*nsv, COS_EPS);
      float c = acc[r] * __builtin_amdgcn_rcpf(denom);
      cosw[(size_t)(b*MM + m)*NN + n] = (unsigned short)(pkh2(c, 0.f) & 0xFFFFu);
    }
  }
}

// ---------------- K3: main. grid (64, 8, 2), 4 waves. 16 n/block; waves split m 4-way ----------------
// Wave w: m = ms*128 + j*4 + w, j=0..31, over the SAME 16 n-columns. h1 B-frags in
// regs, L2 MFMA, h2 LDS transpose (dbuf, 1 lgkm-wait / 2 steps), L3 MFMA, p=max.
// End: 4-way LDS max combine, + c3 + relu, wave 0 stores the partial.
__global__ __launch_bounds__(256, 4) void k_main(const float* ws, float* Pp){
  __shared__ __align__(16) unsigned short h2W[4][2][16][72];  // 18432 B (redBuf overlays)
  int t = threadIdx.x;
  int lane = t & 63, w = t >> 6;
  int ln15 = lane & 15, quad = lane >> 4;
  int b = blockIdx.y;
  int n0 = blockIdx.x * 16;
  int ms = blockIdx.z;

  const float* w2p = ws + WS_W2F;
  const float* w3p = ws + WS_W3F;
  half8 W2A[4][2], W3A[4][2];
  f32x4 c2v[4];
  #pragma unroll
  for (int rt = 0; rt < 4; rt++){
    int g = rt*16 + ln15;
    #pragma unroll
    for (int kk = 0; kk < 2; kk++){
      half8 a2, a3;
      #pragma unroll
      for (int j = 0; j < 8; j++){
        int k = kk*32 + quad*8 + j;
        a2[j] = (_Float16)w2p[g*64 + k];
        a3[j] = (_Float16)w3p[g*64 + k];
      }
      W2A[rt][kk] = a2; W3A[rt][kk] = a3;
    }
    float4 cb2 = *(const float4*)&ws[WS_C2 + rt*16 + quad*4];
    c2v[rt] = (f32x4){cb2.x, cb2.y, cb2.z, cb2.w};
  }
  unsigned int upk[2][4];
  #pragma unroll
  for (int kk = 0; kk < 2; kk++){
    float4 ua = *(const float4*)&ws[WS_U + kk*32 + quad*8];
    float4 ub = *(const float4*)&ws[WS_U + kk*32 + quad*8 + 4];
    upk[kk][0] = pkh2(ua.x, ua.y); upk[kk][1] = pkh2(ua.z, ua.w);
    upk[kk][2] = pkh2(ub.x, ub.y); upk[kk][3] = pkh2(ub.z, ub.w);
  }
  const unsigned short* A1H = (const unsigned short*)(ws + WS_A1) + (size_t)b*MM*64;
  int n = n0 + ln15;
  const unsigned short* cosP = (const unsigned short*)(ws + WS_COSH) + (size_t)b*MM*NN + n;
  unsigned short* h2w0 = &h2W[w][0][0][0];
  unsigned short* h2w1 = &h2W[w][1][0][0];

  f32x4 p[4];
  #pragma unroll
  for (int rt = 0; rt < 4; rt++) p[rt] = (f32x4){-3e38f, -3e38f, -3e38f, -3e38f};
  const f32x4 ZER4 = (f32x4){0.f,0.f,0.f,0.f};

  int mA = ms*128 + 0*4 + w;
  int mB = ms*128 + 1*4 + w;
  unsigned int cuA = cosP[(size_t)mA*NN];
  unsigned int cuB = cosP[(size_t)mB*NN];
  uint4 aAa = *(const uint4*)&A1H[(size_t)mA*64 + quad*8];
  uint4 aAb = *(const uint4*)&A1H[(size_t)mA*64 + 32 + quad*8];
  uint4 aBa = *(const uint4*)&A1H[(size_t)mB*64 + quad*8];
  uint4 aBb = *(const uint4*)&A1H[(size_t)mB*64 + 32 + quad*8];

  for (int j = 0; j < 32; j += 2){
    // ---- step j (buf0): build h1 -> L2 -> write ----
    {
      unsigned int cd = cuA | (cuA << 16);
      half2v ch = u2h(cd);
      uint4 q0, q1;
      q0.x = bh1(upk[0][0], ch, aAa.x); q0.y = bh1(upk[0][1], ch, aAa.y);
      q0.z = bh1(upk[0][2], ch, aAa.z); q0.w = bh1(upk[0][3], ch, aAa.w);
      q1.x = bh1(upk[1][0], ch, aAb.x); q1.y = bh1(upk[1][1], ch, aAb.y);
      q1.z = bh1(upk[1][2], ch, aAb.z); q1.w = bh1(upk[1][3], ch, aAb.w);
      half8 b0h = __builtin_bit_cast(half8, q0);
      half8 b1h = __builtin_bit_cast(half8, q1);
      f32x4 acc[4];
      #pragma unroll
      for (int rt = 0; rt < 4; rt++){
        acc[rt] = __builtin_amdgcn_mfma_f32_16x16x32_f16(W2A[rt][0], b0h, c2v[rt], 0, 0, 0);
        acc[rt] = __builtin_amdgcn_mfma_f32_16x16x32_f16(W2A[rt][1], b1h, acc[rt], 0, 0, 0);
      }
      #pragma unroll
      for (int rt = 0; rt < 4; rt++){
        uint2 vv;
        vv.x = relu2(pkh2(acc[rt][0], acc[rt][1]));
        vv.y = relu2(pkh2(acc[rt][2], acc[rt][3]));
        *(uint2*)&h2w0[ln15*72 + rt*16 + quad*4] = vv;
      }
    }
    // ---- step j+1 (buf1) ----
    {
      unsigned int cd = cuB | (cuB << 16);
      half2v ch = u2h(cd);
      uint4 q0, q1;
      q0.x = bh1(upk[0][0], ch, aBa.x); q0.y = bh1(upk[0][1], ch, aBa.y);
      q0.z = bh1(upk[0][2], ch, aBa.z); q0.w = bh1(upk[0][3], ch, aBa.w);
      q1.x = bh1(upk[1][0], ch, aBb.x); q1.y = bh1(upk[1][1], ch, aBb.y);
      q1.z = bh1(upk[1][2], ch, aBb.z); q1.w = bh1(upk[1][3], ch, aBb.w);
      half8 b0h = __builtin_bit_cast(half8, q0);
      half8 b1h = __builtin_bit_cast(half8, q1);
      f32x4 acc[4];
      #pragma unroll
      for (int rt = 0; rt < 4; rt++){
        acc[rt] = __builtin_amdgcn_mfma_f32_16x16x32_f16(W2A[rt][0], b0h, c2v[rt], 0, 0, 0);
        acc[rt] = __builtin_amdgcn_mfma_f32_16x16x32_f16(W2A[rt][1], b1h, acc[rt], 0, 0, 0);
      }
      #pragma unroll
      for (int rt = 0; rt < 4; rt++){
        uint2 vv;
        vv.x = relu2(pkh2(acc[rt][0], acc[rt][1]));
        vv.y = relu2(pkh2(acc[rt][2], acc[rt][3]));
        *(uint2*)&h2w1[ln15*72 + rt*16 + quad*4] = vv;
      }
    }
    // ---- prefetch steps j+2, j+3 (global loads ride vmcnt past the lgkm wait) ----
    int j2 = (j + 2 < 32) ? j + 2 : 30;
    int j3 = (j + 3 < 32) ? j + 3 : 31;
    int m2i = ms*128 + j2*4 + w;
    int m3i = ms*128 + j3*4 + w;
    unsigned int cuA2 = cosP[(size_t)m2i*NN];
    unsigned int cuB2 = cosP[(size_t)m3i*NN];
    uint4 nAa = *(const uint4*)&A1H[(size_t)m2i*64 + quad*8];
    uint4 nAb = *(const uint4*)&A1H[(size_t)m2i*64 + 32 + quad*8];
    uint4 nBa = *(const uint4*)&A1H[(size_t)m3i*64 + quad*8];
    uint4 nBb = *(const uint4*)&A1H[(size_t)m3i*64 + 32 + quad*8];
    __asm__ volatile("s_waitcnt lgkmcnt(0)" ::: "memory");
    // ---- transposed reads -> L3 -> running max, both bufs ----
    {
      half8 e0 = *(const half8*)&h2w0[ln15*72 + quad*8];
      half8 e1 = *(const half8*)&h2w0[ln15*72 + 32 + quad*8];
      #pragma unroll
      for (int rt = 0; rt < 4; rt++){
        f32x4 a3 = __builtin_amdgcn_mfma_f32_16x16x32_f16(W3A[rt][0], e0, ZER4, 0, 0, 0);
        a3 = __builtin_amdgcn_mfma_f32_16x16x32_f16(W3A[rt][1], e1, a3, 0, 0, 0);
        #pragma unroll
        for (int r = 0; r < 4; r++) p[rt][r] = fmaxf(p[rt][r], a3[r]);
      }
      half8 f0 = *(const half8*)&h2w1[ln15*72 + quad*8];
      half8 f1 = *(const half8*)&h2w1[ln15*72 + 32 + quad*8];
      #pragma unroll
      for (int rt = 0; rt < 4; rt++){
        f32x4 a3 = __builtin_amdgcn_mfma_f32_16x16x32_f16(W3A[rt][0], f0, ZER4, 0, 0, 0);
        a3 = __builtin_amdgcn_mfma_f32_16x16x32_f16(W3A[rt][1], f1, a3, 0, 0, 0);
        #pragma unroll
        for (int r = 0; r < 4; r++) p[rt][r] = fmaxf(p[rt][r], a3[r]);
      }
    }
    cuA = cuA2; cuB = cuB2;
    aAa = nAa; aAb = nAb; aBa = nBa; aBb = nBb;
  }

  // ---- 4-way cross-wave max combine (all waves share the same (n,g) territory,
  //      disjoint m — merge required; plain store would race, cf. R7) ----
  __syncthreads();
  float* redBuf = (float*)&h2W[0][0][0][0];   // 4608 floats avail; use 3*1088
  if (w >= 1){
    #pragma unroll
    for (int rt = 0; rt < 4; rt++){
      f32x4 v = p[rt];
      *(float4*)&redBuf[(size_t)((w-1)*1088 + ln15*68 + rt*16 + quad*4)] =
          make_float4(v[0], v[1], v[2], v[3]);
    }
  }
  __syncthreads();
  if (w == 0){
    float* Pb = Pp + (size_t)ms*PS + ((size_t)(b*NN + n) << 6);
    #pragma unroll
    for (int rt = 0; rt < 4; rt++){
      int off = ln15*68 + rt*16 + quad*4;
      float4 o1 = *(const float4*)&redBuf[off];
      float4 o2 = *(const float4*)&redBuf[1088 + off];
      float4 o3 = *(const float4*)&redBuf[2176 + off];
      float4 c3r = *(const float4*)&ws[WS_C3 + rt*16 + quad*4];
      float4 r4;
      r4.x = fmaxf(fmaxf(fmaxf(p[rt][0], o1.x), fmaxf(o2.x, o3.x)) + c3r.x, 0.f);
      r4.y = fmaxf(fmaxf(fmaxf(p[rt][1], o1.y), fmaxf(o2.y, o3.y)) + c3r.y, 0.f);
      r4.z = fmaxf(fmaxf(fmaxf(p[rt][2], o1.z), fmaxf(o2.z, o3.z)) + c3r.z, 0.f);
      r4.w = fmaxf(fmaxf(fmaxf(p[rt][3], o1.w), fmaxf(o2.w, o3.w)) + c3r.w, 0.f);
      *(float4*)&Pb[rt*16 + quad*4] = r4;
    }
  }
}

// ---------------- K4: tail (max 2 partials, Wc1f/relu, Wc2+bias) fp32 ----------------
__global__ __launch_bounds__(256) void k_tail(const float* Wc2, const float* bc2,
                                              const float* ws, float* out){
  __shared__ float WT[64][68];
  __shared__ float pT[32][68];
  __shared__ float cS[32][68];
  int t = threadIdx.x;
  int n0 = blockIdx.x * 32;
  int b = blockIdx.y;
  for (int i = t; i < 4096; i += 256) WT[i >> 6][i & 63] = ws[WS_WC1F + i];
  const float* P0 = ws + WS_P + ((size_t)(b*NN + n0) << 6);
  const float* P1 = P0 + PS;
  for (int i = t; i < 2048; i += 256) pT[i >> 6][i & 63] = fmaxf(P0[i], P1[i]);
  __syncthreads();
  {
    int n = t & 31, q = t >> 5;
    for (int k = 0; k < 8; k++){
      int g = q*8 + k;
      float acc = ws[WS_CC1 + g];
      for (int hs = 0; hs < 64; hs += 4){
        float4 wv = *(const float4*)&WT[g][hs];
        float4 pv = *(const float4*)&pT[n][hs];
        acc = dot4(wv, pv, acc);
      }
      cS[n][g] = fmaxf(acc, 0.f);
    }
  }
  __syncthreads();
  {
    int o = t & 127, hf = t >> 7;
    float bco = bc2[o];
    float accO[16];
    #pragma unroll
    for (int i = 0; i < 16; i++) accO[i] = bco;
    for (int hs = 0; hs < 64; hs += 4){
      float4 w4 = *(const float4*)&Wc2[o*64 + hs];
      #pragma unroll
      for (int i = 0; i < 16; i++){
        float4 cv = *(const float4*)&cS[hf*16 + i][hs];
        accO[i] = dot4(w4, cv, accO[i]);
      }
    }
    #pragma unroll
    for (int i = 0; i < 16; i++)
      out[((size_t)(b*OO + o))*NN + n0 + hf*16 + i] = accO[i];
  }
}

extern "C" void kernel_launch(void* const* d_in, const int* in_sizes, int n_in,
                              void* d_out, int out_size, void* d_ws, size_t ws_size,
                              hipStream_t stream){
  (void)in_sizes; (void)n_in; (void)out_size; (void)ws_size;
  const float* t_  = (const float*)d_in[0];
  const float* s_  = (const float*)d_in[1];
  const float* W1  = (const float*)d_in[2];
  const float* W2  = (const float*)d_in[3];
  const float* W3  = (const float*)d_in[4];
  const float* Wc1 = (const float*)d_in[5];
  const float* Wc2 = (const float*)d_in[6];
  const float* bc2 = (const float*)d_in[7];
  const float* g1 = (const float*)d_in[8],  *b1 = (const float*)d_in[9],
             * m1 = (const float*)d_in[10], *v1 = (const float*)d_in[11];
  const float* g2 = (const float*)d_in[12], *b2 = (const float*)d_in[13],
             * m2 = (const float*)d_in[14], *v2 = (const float*)d_in[15];
  const float* g3 = (const float*)d_in[16], *b3 = (const float*)d_in[17],
             * m3 = (const float*)d_in[18], *v3 = (const float*)d_in[19];
  const float* gc1 = (const float*)d_in[20], *bc1 = (const float*)d_in[21],
             * mc1 = (const float*)d_in[22], *vc1 = (const float*)d_in[23];
  float* ws = (float*)d_ws;
  float* out = (float*)d_out;

  k_prep<<<417, 256, 0, stream>>>(t_, s_, W1, W2, W3, Wc1,
      g1,b1,m1,v1, g2,b2,m2,v2, g3,b3,m3,v3, gc1,bc1,mc1,vc1, ws);
  k_cos<<<dim3(4, 16, 8), 256, 0, stream>>>(ws);
  k_main<<<dim3(64, 8, 2), 256, 0, stream>>>(ws, ws + WS_P);
  k_tail<<<dim3(32, 8), 256, 0, stream>>>(Wc2, bc2, ws, out);
}

// Round 11
// 225.623 us; speedup vs baseline: 1.1143x; 1.1143x over previous
//
#include <hip/hip_runtime.h>

// P2B_XCorr: B=8, F=128, M=256, N=1024, H=64, O=128. fp32 I/O.
// R11: kill k_main's HBM amplification (R10: FETCH 39.6 MB + WRITE 64.5 MB at 875 GB/s
//   == the whole 119 us; [m][n]-major cos made every access a 32B nibble of a line
//   shared across XCDs).
//   - cos stored TILED: [b][n-tile 64][m 256][16 n] f16 -> k_cos stores 128B-dense;
//     k_main's per-block cos slab is one contiguous 4 KB run.
//   - k_main stages cos (4KB) + A1 m-half (16KB) into LDS once (coalesced uint4);
//     the m-loop has ZERO global loads; in-loop prefetch = ds_reads behind the same
//     per-pair lgkmcnt(0). Waves own contiguous 32-m runs; 4-way LDS max combine.
//   LDS 38.9 KB -> 4 blocks/CU.
// Frag layouts (HW-verified): A[m=lane&15][k=quad*8+j], B[k=quad*8+j][n=lane&15],
// D[row=quad*4+reg][col=lane&15].

#define BB 8
#define FF 128
#define MM 256
#define NN 1024
#define HH 64
#define OO 128
#define BN_EPS 1e-5f
#define COS_EPS 1e-8f

// ws layout (float offsets); max used 2,175,232 < proven 2,251,008 envelope
#define WS_U     0
#define WS_C2    64
#define WS_C3    128
#define WS_CC1   192
#define WS_W2F   256
#define WS_W3F   4352
#define WS_WC1F  8448
#define WS_A1    12544        // f16 A1H[b][m][64] -> ends 78080
#define WS_COSH  78080        // f16 cos TILED [b][64][256][16] -> ends 1,126,656
#define WS_TH    1126656      // u32 tH[b][64 fpair][256 m] (k_cos only)
#define WS_SH    1257728      // u32 sH[b][64 fpair][1024 n] (k_cos only)
#define WS_NT    1782016      // fp32 [b][m] (k_cos only)
#define WS_NS    1784064      // fp32 [b][n] (k_cos only)
#define WS_P     1126656      // OVERLAY: fp32 partials [2][b][n][64] -> ends 2,175,232
#define PS       524288

typedef _Float16 half2v __attribute__((ext_vector_type(2)));
typedef _Float16 half8  __attribute__((ext_vector_type(8)));
typedef __attribute__((ext_vector_type(4))) float f32x4;

__device__ __forceinline__ unsigned int pkh2(float a, float b){
  auto h = __builtin_amdgcn_cvt_pkrtz(a, b);
  return __builtin_bit_cast(unsigned int, h);
}
__device__ __forceinline__ half2v u2h(unsigned int u){
  return __builtin_bit_cast(half2v, u);
}
__device__ __forceinline__ unsigned int h2u(half2v v){
  return __builtin_bit_cast(unsigned int, v);
}
__device__ __forceinline__ unsigned int relu2(unsigned int d){
  half2v v = __builtin_elementwise_max(u2h(d), (half2v){(_Float16)0, (_Float16)0});
  return h2u(v);
}
__device__ __forceinline__ unsigned int bh1(unsigned int up, half2v c, unsigned int ap){
  half2v v = __builtin_elementwise_fma(u2h(up), c, u2h(ap));
  v = __builtin_elementwise_max(v, (half2v){(_Float16)0, (_Float16)0});
  return h2u(v);
}
__device__ __forceinline__ float dot4(float4 a, float4 b, float acc){
  acc = fmaf(a.x, b.x, acc); acc = fmaf(a.y, b.y, acc);
  acc = fmaf(a.z, b.z, acc); acc = fmaf(a.w, b.w, acc);
  return acc;
}

// ---------------- K1: prep (role-split: a1 | norms+f16 pack | fold) ----------------
__global__ __launch_bounds__(256) void k_prep(const float* t_, const float* s_,
    const float* W1, const float* W2, const float* W3, const float* Wc1,
    const float* g1, const float* b1, const float* m1, const float* v1,
    const float* g2, const float* b2, const float* m2, const float* v2,
    const float* g3, const float* b3, const float* m3, const float* v3,
    const float* gc1,const float* bc1,const float* mc1,const float* vc1,
    float* ws){
  __shared__ float W1s[64][133];
  int t = threadIdx.x;
  int bx = blockIdx.x;
  if (bx < 256){
    // ---- A1H[b][m][h] (f16) ----
    int b = bx >> 5, m0 = (bx & 31)*8;
    for (int idx = t; idx < 8192; idx += 256){
      int h = idx >> 7, f = idx & 127;
      W1s[h][f] = W1[h*129 + 1 + f];
    }
    __syncthreads();
    int h = t & 63, mg = t >> 6;
    const float* tp = t_ + (size_t)b*FF*MM + m0 + mg*2;
    float acc0 = 0.f, acc1 = 0.f;
    for (int f = 0; f < FF; f++){
      float wv = W1s[h][f];
      float2 tv = *(const float2*)&tp[(size_t)f*MM];
      acc0 = fmaf(wv, tv.x, acc0); acc1 = fmaf(wv, tv.y, acc1);
    }
    float a1 = g1[h] / sqrtf(v1[h] + BN_EPS);
    float c1 = b1[h] - a1*m1[h];
    unsigned short* dst = (unsigned short*)(ws + WS_A1) + ((size_t)(b*MM + m0 + mg*2))*64 + h;
    dst[0]  = (unsigned short)(pkh2(fmaf(a1, acc0, c1), 0.f) & 0xFFFFu);
    dst[64] = (unsigned short)(pkh2(fmaf(a1, acc1, c1), 0.f) & 0xFFFFu);
  } else if (bx < 416){
    // ---- norms + f16 pack of t/s ----
    __shared__ float red[4][64];
    unsigned int* thp = (unsigned int*)(ws + WS_TH);
    unsigned int* shp = (unsigned int*)(ws + WS_SH);
    int x = t & 63, fq = t >> 6;
    int idx = (bx - 256)*64 + x;
    float acc = 0.f;
    if (idx < BB*MM){
      int b = idx >> 8, m = idx & 255;
      const float* ptr = t_ + (size_t)b*FF*MM + m;
      #pragma unroll
      for (int k = 0; k < 16; k++){
        int f = fq*32 + 2*k;
        float va = ptr[(size_t)f*MM], vb = ptr[(size_t)(f+1)*MM];
        acc = fmaf(va, va, acc); acc = fmaf(vb, vb, acc);
        thp[(size_t)(b*64 + fq*16 + k)*MM + m] = pkh2(va, vb);
      }
    } else {
      int j = idx - BB*MM;
      int b = j >> 10, n = j & 1023;
      const float* ptr = s_ + (size_t)b*FF*NN + n;
      #pragma unroll
      for (int k = 0; k < 16; k++){
        int f = fq*32 + 2*k;
        float va = ptr[(size_t)f*NN], vb = ptr[(size_t)(f+1)*NN];
        acc = fmaf(va, va, acc); acc = fmaf(vb, vb, acc);
        shp[(size_t)(b*64 + fq*16 + k)*NN + n] = pkh2(va, vb);
      }
    }
    red[fq][x] = acc;
    __syncthreads();
    if (fq == 0)
      ws[WS_NT + idx] = sqrtf(red[0][x] + red[1][x] + red[2][x] + red[3][x]);
  } else {
    // ---- fold ----
    if (t < 64){
      float a1 = g1[t] / sqrtf(v1[t] + BN_EPS);
      ws[WS_U + t]   = a1 * W1[t*129];
      float a2 = g2[t] / sqrtf(v2[t] + BN_EPS);
      ws[WS_C2 + t]  = b2[t] - a2*m2[t];
      float a3 = g3[t] / sqrtf(v3[t] + BN_EPS);
      ws[WS_C3 + t]  = b3[t] - a3*m3[t];
      float ac = gc1[t] / sqrtf(vc1[t] + BN_EPS);
      ws[WS_CC1 + t] = bc1[t] - ac*mc1[t];
    }
    for (int i = t; i < 4096; i += 256){
      int g = i >> 6;
      float a2 = g2[g] / sqrtf(v2[g] + BN_EPS);
      ws[WS_W2F + i]  = a2 * W2[i];
      float a3 = g3[g] / sqrtf(v3[g] + BN_EPS);
      ws[WS_W3F + i]  = a3 * W3[i];
      float ac = gc1[g] / sqrtf(vc1[g] + BN_EPS);
      ws[WS_WC1F + i] = ac * Wc1[i];
    }
  }
}

// ---------------- K2: cos via f16 MFMA, staged from packed tH/sH; TILED store ----------------
__global__ __launch_bounds__(256) void k_cos(float* ws){
  __shared__ __align__(16) unsigned short tS[64][136];
  __shared__ __align__(16) unsigned short sS[64][136];
  __shared__ float ntS[64], nsS[64];
  int t = threadIdx.x;
  int lane = t & 63, w = t >> 6;
  int ln15 = lane & 15, quad = lane >> 4;
  int m0 = blockIdx.x*64, n0 = blockIdx.y*64, b = blockIdx.z;
  {
    const unsigned int* thp = (const unsigned int*)(ws + WS_TH);
    const unsigned int* shp = (const unsigned int*)(ws + WS_SH);
    for (int i = t; i < 4096; i += 256){
      int x = i & 63, fp = i >> 6;
      *(unsigned int*)&tS[x][2*fp] = thp[(size_t)(b*64 + fp)*MM + m0 + x];
      *(unsigned int*)&sS[x][2*fp] = shp[(size_t)(b*64 + fp)*NN + n0 + x];
    }
    if (t < 64) ntS[t] = ws[WS_NT + b*MM + m0 + t];
    else if (t < 128) nsS[t-64] = ws[WS_NS + b*NN + n0 + (t-64)];
  }
  __syncthreads();
  half8 A4[4];
  #pragma unroll
  for (int kc = 0; kc < 4; kc++)
    A4[kc] = *(const half8*)&tS[w*16 + ln15][kc*32 + quad*8];
  float4 nt4 = *(const float4*)&ntS[w*16 + quad*4];
  unsigned short* cosw = (unsigned short*)(ws + WS_COSH);
  #pragma unroll
  for (int ns = 0; ns < 4; ns++){
    f32x4 acc = (f32x4){0.f,0.f,0.f,0.f};
    #pragma unroll
    for (int kc = 0; kc < 4; kc++){
      half8 B4 = *(const half8*)&sS[ns*16 + ln15][kc*32 + quad*8];
      acc = __builtin_amdgcn_mfma_f32_16x16x32_f16(A4[kc], B4, acc, 0, 0, 0);
    }
    float nsv = nsS[ns*16 + ln15];
    int tile = (n0 >> 4) + ns;
    #pragma unroll
    for (int r = 0; r < 4; r++){
      int m = m0 + w*16 + quad*4 + r;
      float denom = fmaxf(nt4[r]*nsv, COS_EPS);
      float c = acc[r] * __builtin_amdgcn_rcpf(denom);
      // tiled: [b][tile][m][16]
      cosw[((size_t)(b*64 + tile)*256 + m)*16 + ln15] = (unsigned short)(pkh2(c, 0.f) & 0xFFFFu);
    }
  }
}

// ---------------- K3: main. grid (64, 8, 2), 4 waves; wave w owns m-run w*32..+31 ----------------
// Stage cos slab (4KB) + A1 m-half (16KB) into LDS (dense uint4). Loop: h1 B-frag in
// regs from LDS cos/A1, L2 MFMA, h2 LDS transpose (dbuf, 1 lgkm-wait / 2 steps, LDS
// prefetch before the wait), L3 MFMA, p=max. End: 4-way LDS max combine + c3 + relu.
__global__ __launch_bounds__(256, 4) void k_main(const float* ws, float* Pp){
  __shared__ __align__(16) unsigned short h2W[4][2][16][72];  // 18432 B
  __shared__ __align__(16) unsigned short cosL[128][16];      // 4096 B
  __shared__ __align__(16) unsigned short A1L[128][64];       // 16384 B (redBuf overlay)
  int t = threadIdx.x;
  int lane = t & 63, w = t >> 6;
  int ln15 = lane & 15, quad = lane >> 4;
  int b = blockIdx.y;
  int n0 = blockIdx.x * 16;
  int ms = blockIdx.z;

  // ---- cooperative dense staging ----
  {
    const uint4* cs = (const uint4*)((const unsigned short*)(ws + WS_COSH)
        + ((size_t)(b*64 + blockIdx.x)*256 + ms*128)*16);
    ((uint4*)cosL)[t] = cs[t];
    const uint4* as = (const uint4*)((const unsigned short*)(ws + WS_A1)
        + ((size_t)(b*MM + ms*128))*64);
    uint4* ad = (uint4*)A1L;
    #pragma unroll
    for (int k = 0; k < 4; k++) ad[t + 256*k] = as[t + 256*k];
  }

  const float* w2p = ws + WS_W2F;
  const float* w3p = ws + WS_W3F;
  half8 W2A[4][2], W3A[4][2];
  f32x4 c2v[4];
  #pragma unroll
  for (int rt = 0; rt < 4; rt++){
    int g = rt*16 + ln15;
    #pragma unroll
    for (int kk = 0; kk < 2; kk++){
      half8 a2, a3;
      #pragma unroll
      for (int j = 0; j < 8; j++){
        int k = kk*32 + quad*8 + j;
        a2[j] = (_Float16)w2p[g*64 + k];
        a3[j] = (_Float16)w3p[g*64 + k];
      }
      W2A[rt][kk] = a2; W3A[rt][kk] = a3;
    }
    float4 cb2 = *(const float4*)&ws[WS_C2 + rt*16 + quad*4];
    c2v[rt] = (f32x4){cb2.x, cb2.y, cb2.z, cb2.w};
  }
  unsigned int upk[2][4];
  #pragma unroll
  for (int kk = 0; kk < 2; kk++){
    float4 ua = *(const float4*)&ws[WS_U + kk*32 + quad*8];
    float4 ub = *(const float4*)&ws[WS_U + kk*32 + quad*8 + 4];
    upk[kk][0] = pkh2(ua.x, ua.y); upk[kk][1] = pkh2(ua.z, ua.w);
    upk[kk][2] = pkh2(ub.x, ub.y); upk[kk][3] = pkh2(ub.z, ub.w);
  }
  int n = n0 + ln15;
  unsigned short* h2w0 = &h2W[w][0][0][0];
  unsigned short* h2w1 = &h2W[w][1][0][0];

  f32x4 p[4];
  #pragma unroll
  for (int rt = 0; rt < 4; rt++) p[rt] = (f32x4){-3e38f, -3e38f, -3e38f, -3e38f};
  const f32x4 ZER4 = (f32x4){0.f,0.f,0.f,0.f};

  __syncthreads();   // staging complete

  int mlB = w*32;    // wave's local m base
  unsigned int cuA = cosL[mlB + 0][ln15];
  unsigned int cuB = cosL[mlB + 1][ln15];
  uint4 aAa = *(const uint4*)&A1L[mlB + 0][quad*8];
  uint4 aAb = *(const uint4*)&A1L[mlB + 0][32 + quad*8];
  uint4 aBa = *(const uint4*)&A1L[mlB + 1][quad*8];
  uint4 aBb = *(const uint4*)&A1L[mlB + 1][32 + quad*8];

  for (int j = 0; j < 32; j += 2){
    // ---- step j (buf0): build h1 -> L2 -> write ----
    {
      unsigned int cd = cuA | (cuA << 16);
      half2v ch = u2h(cd);
      uint4 q0, q1;
      q0.x = bh1(upk[0][0], ch, aAa.x); q0.y = bh1(upk[0][1], ch, aAa.y);
      q0.z = bh1(upk[0][2], ch, aAa.z); q0.w = bh1(upk[0][3], ch, aAa.w);
      q1.x = bh1(upk[1][0], ch, aAb.x); q1.y = bh1(upk[1][1], ch, aAb.y);
      q1.z = bh1(upk[1][2], ch, aAb.z); q1.w = bh1(upk[1][3], ch, aAb.w);
      half8 b0h = __builtin_bit_cast(half8, q0);
      half8 b1h = __builtin_bit_cast(half8, q1);
      f32x4 acc[4];
      #pragma unroll
      for (int rt = 0; rt < 4; rt++){
        acc[rt] = __builtin_amdgcn_mfma_f32_16x16x32_f16(W2A[rt][0], b0h, c2v[rt], 0, 0, 0);
        acc[rt] = __builtin_amdgcn_mfma_f32_16x16x32_f16(W2A[rt][1], b1h, acc[rt], 0, 0, 0);
      }
      #pragma unroll
      for (int rt = 0; rt < 4; rt++){
        uint2 vv;
        vv.x = relu2(pkh2(acc[rt][0], acc[rt][1]));
        vv.y = relu2(pkh2(acc[rt][2], acc[rt][3]));
        *(uint2*)&h2w0[ln15*72 + rt*16 + quad*4] = vv;
      }
    }
    // ---- step j+1 (buf1) ----
    {
      unsigned int cd = cuB | (cuB << 16);
      half2v ch = u2h(cd);
      uint4 q0, q1;
      q0.x = bh1(upk[0][0], ch, aBa.x); q0.y = bh1(upk[0][1], ch, aBa.y);
      q0.z = bh1(upk[0][2], ch, aBa.z); q0.w = bh1(upk[0][3], ch, aBa.w);
      q1.x = bh1(upk[1][0], ch, aBb.x); q1.y = bh1(upk[1][1], ch, aBb.y);
      q1.z = bh1(upk[1][2], ch, aBb.z); q1.w = bh1(upk[1][3], ch, aBb.w);
      half8 b0h = __builtin_bit_cast(half8, q0);
      half8 b1h = __builtin_bit_cast(half8, q1);
      f32x4 acc[4];
      #pragma unroll
      for (int rt = 0; rt < 4; rt++){
        acc[rt] = __builtin_amdgcn_mfma_f32_16x16x32_f16(W2A[rt][0], b0h, c2v[rt], 0, 0, 0);
        acc[rt] = __builtin_amdgcn_mfma_f32_16x16x32_f16(W2A[rt][1], b1h, acc[rt], 0, 0, 0);
      }
      #pragma unroll
      for (int rt = 0; rt < 4; rt++){
        uint2 vv;
        vv.x = relu2(pkh2(acc[rt][0], acc[rt][1]));
        vv.y = relu2(pkh2(acc[rt][2], acc[rt][3]));
        *(uint2*)&h2w1[ln15*72 + rt*16 + quad*4] = vv;
      }
    }
    // ---- prefetch next pair from LDS (drained by the same lgkm wait) ----
    int j2 = (j + 2 < 32) ? j + 2 : 30;
    int j3 = (j + 3 < 32) ? j + 3 : 31;
    unsigned int cuA2 = cosL[mlB + j2][ln15];
    unsigned int cuB2 = cosL[mlB + j3][ln15];
    uint4 nAa = *(const uint4*)&A1L[mlB + j2][quad*8];
    uint4 nAb = *(const uint4*)&A1L[mlB + j2][32 + quad*8];
    uint4 nBa = *(const uint4*)&A1L[mlB + j3][quad*8];
    uint4 nBb = *(const uint4*)&A1L[mlB + j3][32 + quad*8];
    __asm__ volatile("s_waitcnt lgkmcnt(0)" ::: "memory");
    // ---- transposed reads -> L3 -> running max, both bufs ----
    {
      half8 e0 = *(const half8*)&h2w0[ln15*72 + quad*8];
      half8 e1 = *(const half8*)&h2w0[ln15*72 + 32 + quad*8];
      #pragma unroll
      for (int rt = 0; rt < 4; rt++){
        f32x4 a3 = __builtin_amdgcn_mfma_f32_16x16x32_f16(W3A[rt][0], e0, ZER4, 0, 0, 0);
        a3 = __builtin_amdgcn_mfma_f32_16x16x32_f16(W3A[rt][1], e1, a3, 0, 0, 0);
        #pragma unroll
        for (int r = 0; r < 4; r++) p[rt][r] = fmaxf(p[rt][r], a3[r]);
      }
      half8 f0 = *(const half8*)&h2w1[ln15*72 + quad*8];
      half8 f1 = *(const half8*)&h2w1[ln15*72 + 32 + quad*8];
      #pragma unroll
      for (int rt = 0; rt < 4; rt++){
        f32x4 a3 = __builtin_amdgcn_mfma_f32_16x16x32_f16(W3A[rt][0], f0, ZER4, 0, 0, 0);
        a3 = __builtin_amdgcn_mfma_f32_16x16x32_f16(W3A[rt][1], f1, a3, 0, 0, 0);
        #pragma unroll
        for (int r = 0; r < 4; r++) p[rt][r] = fmaxf(p[rt][r], a3[r]);
      }
    }
    cuA = cuA2; cuB = cuB2;
    aAa = nAa; aAb = nAb; aBa = nBa; aBb = nBb;
  }

  // ---- 4-way cross-wave max combine (disjoint m, same (n,g)) + c3 + relu + store ----
  __syncthreads();
  float* redBuf = (float*)&A1L[0][0];   // A1L dead; 4096 floats avail, use 3*1088
  if (w >= 1){
    #pragma unroll
    for (int rt = 0; rt < 4; rt++){
      f32x4 v = p[rt];
      *(float4*)&redBuf[(size_t)((w-1)*1088 + ln15*68 + rt*16 + quad*4)] =
          make_float4(v[0], v[1], v[2], v[3]);
    }
  }
  __syncthreads();
  if (w == 0){
    float* Pb = Pp + (size_t)ms*PS + ((size_t)(b*NN + n) << 6);
    #pragma unroll
    for (int rt = 0; rt < 4; rt++){
      int off = ln15*68 + rt*16 + quad*4;
      float4 o1 = *(const float4*)&redBuf[off];
      float4 o2 = *(const float4*)&redBuf[1088 + off];
      float4 o3 = *(const float4*)&redBuf[2176 + off];
      float4 c3r = *(const float4*)&ws[WS_C3 + rt*16 + quad*4];
      float4 r4;
      r4.x = fmaxf(fmaxf(fmaxf(p[rt][0], o1.x), fmaxf(o2.x, o3.x)) + c3r.x, 0.f);
      r4.y = fmaxf(fmaxf(fmaxf(p[rt][1], o1.y), fmaxf(o2.y, o3.y)) + c3r.y, 0.f);
      r4.z = fmaxf(fmaxf(fmaxf(p[rt][2], o1.z), fmaxf(o2.z, o3.z)) + c3r.z, 0.f);
      r4.w = fmaxf(fmaxf(fmaxf(p[rt][3], o1.w), fmaxf(o2.w, o3.w)) + c3r.w, 0.f);
      *(float4*)&Pb[rt*16 + quad*4] = r4;
    }
  }
}

// ---------------- K4: tail (max 2 partials, Wc1f/relu, Wc2+bias) fp32 ----------------
__global__ __launch_bounds__(256) void k_tail(const float* Wc2, const float* bc2,
                                              const float* ws, float* out){
  __shared__ float WT[64][68];
  __shared__ float pT[32][68];
  __shared__ float cS[32][68];
  int t = threadIdx.x;
  int n0 = blockIdx.x * 32;
  int b = blockIdx.y;
  for (int i = t; i < 4096; i += 256) WT[i >> 6][i & 63] = ws[WS_WC1F + i];
  const float* P0 = ws + WS_P + ((size_t)(b*NN + n0) << 6);
  const float* P1 = P0 + PS;
  for (int i = t; i < 2048; i += 256) pT[i >> 6][i & 63] = fmaxf(P0[i], P1[i]);
  __syncthreads();
  {
    int n = t & 31, q = t >> 5;
    for (int k = 0; k < 8; k++){
      int g = q*8 + k;
      float acc = ws[WS_CC1 + g];
      for (int hs = 0; hs < 64; hs += 4){
        float4 wv = *(const float4*)&WT[g][hs];
        float4 pv = *(const float4*)&pT[n][hs];
        acc = dot4(wv, pv, acc);
      }
      cS[n][g] = fmaxf(acc, 0.f);
    }
  }
  __syncthreads();
  {
    int o = t & 127, hf = t >> 7;
    float bco = bc2[o];
    float accO[16];
    #pragma unroll
    for (int i = 0; i < 16; i++) accO[i] = bco;
    for (int hs = 0; hs < 64; hs += 4){
      float4 w4 = *(const float4*)&Wc2[o*64 + hs];
      #pragma unroll
      for (int i = 0; i < 16; i++){
        float4 cv = *(const float4*)&cS[hf*16 + i][hs];
        accO[i] = dot4(w4, cv, accO[i]);
      }
    }
    #pragma unroll
    for (int i = 0; i < 16; i++)
      out[((size_t)(b*OO + o))*NN + n0 + hf*16 + i] = accO[i];
  }
}

extern "C" void kernel_launch(void* const* d_in, const int* in_sizes, int n_in,
                              void* d_out, int out_size, void* d_ws, size_t ws_size,
                              hipStream_t stream){
  (void)in_sizes; (void)n_in; (void)out_size; (void)ws_size;
  const float* t_  = (const float*)d_in[0];
  const float* s_  = (const float*)d_in[1];
  const float* W1  = (const float*)d_in[2];
  const float* W2  = (const float*)d_in[3];
  const float* W3  = (const float*)d_in[4];
  const float* Wc1 = (const float*)d_in[5];
  const float* Wc2 = (const float*)d_in[6];
  const float* bc2 = (const float*)d_in[7];
  const float* g1 = (const float*)d_in[8],  *b1 = (const float*)d_in[9],
             * m1 = (const float*)d_in[10], *v1 = (const float*)d_in[11];
  const float* g2 = (const float*)d_in[12], *b2 = (const float*)d_in[13],
             * m2 = (const float*)d_in[14], *v2 = (const float*)d_in[15];
  const float* g3 = (const float*)d_in[16], *b3 = (const float*)d_in[17],
             * m3 = (const float*)d_in[18], *v3 = (const float*)d_in[19];
  const float* gc1 = (const float*)d_in[20], *bc1 = (const float*)d_in[21],
             * mc1 = (const float*)d_in[22], *vc1 = (const float*)d_in[23];
  float* ws = (float*)d_ws;
  float* out = (float*)d_out;

  k_prep<<<417, 256, 0, stream>>>(t_, s_, W1, W2, W3, Wc1,
      g1,b1,m1,v1, g2,b2,m2,v2, g3,b3,m3,v3, gc1,bc1,mc1,vc1, ws);
  k_cos<<<dim3(4, 16, 8), 256, 0, stream>>>(ws);
  k_main<<<dim3(64, 8, 2), 256, 0, stream>>>(ws, ws + WS_P);
  k_tail<<<dim3(32, 8), 256, 0, stream>>>(Wc2, bc2, ws, out);
}